// Round 7
// baseline (232.524 us; speedup 1.0000x reference)
//
#include <hip/hip_runtime.h>
#include <hip/hip_cooperative_groups.h>
#include <hip/hip_bf16.h>
#include <math.h>

namespace cg = cooperative_groups;

// SpatialAxialAttention: B*T=2, H=W=16, dim=1024, HEADS=16, DIM_HEAD=64, K=144
#define BTN   2
#define NH    16
#define SEQ   256
#define DH    64
#define DIMF  1024
#define KTOP  144
#define QT    16
#define PI_F  3.14159265358979323846f

typedef _Float16 half8 __attribute__((ext_vector_type(8)));
typedef _Float16 half4v __attribute__((ext_vector_type(4)));
typedef float f32x4 __attribute__((ext_vector_type(4)));

#define GLDS(src, dst) __builtin_amdgcn_global_load_lds( \
        (const __attribute__((address_space(1))) void*)(src), \
        (__attribute__((address_space(3))) void*)(dst), 16, 0, 0)

#define N0Q (524288 / 4)     // x float4-groups
#define N1Q (3145728 / 4)    // w_qkv
#define N2Q (1048576 / 4)    // w_out
#define NTOT (N0Q + N1Q + N2Q)

// ---------------------------------------------------------------------------
// device tile bodies (verified in rounds 3-6)
// ---------------------------------------------------------------------------
template <int MODE>
__device__ __forceinline__ void gemm_tile(
    const _Float16* __restrict__ A, const _Float16* __restrict__ B,
    int Kd, int N, int row0, int col0,
    _Float16* __restrict__ qb, _Float16* __restrict__ kb, _Float16* __restrict__ vb,
    const float* __restrict__ bias, float* __restrict__ out,
    _Float16* As, _Float16* Bs)
{
    const int tid  = threadIdx.x;
    const int wave = tid >> 6;
    const int lane = tid & 63;
    const int wr = (wave >> 1) * 32;
    const int wc = (wave & 1) * 32;
    const int rl = lane >> 3;
    const int cl = lane & 7;

    f32x4 acc[2][2] = {};

    for (int kt = 0; kt < Kd; kt += 64) {
        __syncthreads();
#pragma unroll
        for (int h = 0; h < 2; ++h) {
            const int rbase = wave * 16 + h * 8;
            const int rA = rbase + rl;
            const _Float16* srcA = A + (size_t)(row0 + rA) * Kd + kt + ((cl ^ (rA & 7)) * 8);
            const _Float16* srcB = B + (size_t)(col0 + rA) * Kd + kt + ((cl ^ (rA & 7)) * 8);
            GLDS(srcA, As + rbase * 64);
            GLDS(srcB, Bs + rbase * 64);
        }
        __syncthreads();

#pragma unroll
        for (int kh = 0; kh < 2; ++kh) {
            half8 a[2], b[2];
            const int g = kh * 4 + (lane >> 4);
#pragma unroll
            for (int i = 0; i < 2; ++i) {
                const int ra = wr + i * 16 + (lane & 15);
                const int rb = wc + i * 16 + (lane & 15);
                a[i] = *(const half8*)(As + ra * 64 + ((g ^ (ra & 7)) * 8));
                b[i] = *(const half8*)(Bs + rb * 64 + ((g ^ (rb & 7)) * 8));
            }
#pragma unroll
            for (int i = 0; i < 2; ++i)
#pragma unroll
                for (int j = 0; j < 2; ++j)
                    acc[i][j] = __builtin_amdgcn_mfma_f32_16x16x32_f16(a[i], b[j], acc[i][j], 0, 0, 0);
        }
    }

    if (MODE == 0) {
#pragma unroll
        for (int i = 0; i < 2; ++i) {
#pragma unroll
            for (int reg = 0; reg < 4; ++reg) {
                const int r  = row0 + wr + i * 16 + (lane >> 4) * 4 + reg;
                const int bt = r >> 8;
                const int s  = r & 255;
                const int hh = s >> 4;
                const int ww = s & 15;
#pragma unroll
                for (int j = 0; j < 2; ++j) {
                    const float v     = acc[i][j][reg];
                    const float other = __shfl_xor(v, 1);   // RoPE pair partner
                    const int n    = col0 + wc + j * 16 + (lane & 15);
                    const int sec  = n >> 10;       // 0=q,1=k,2=v
                    const int oi   = n & 1023;
                    const int head = oi >> 6;
                    const int d    = oi & 63;
                    if (sec == 2) {
                        vb[(((size_t)(bt * NH + head)) * DH + d) * SEQ + s] = (_Float16)v;
                    } else {
                        const int de  = d & ~1;
                        const int j2  = (de < 32) ? (de >> 1) : ((de - 32) >> 1);
                        const float pos = (de < 32) ? (-1.f + hh * (2.f / 15.f))
                                                    : (-1.f + ww * (2.f / 15.f));
                        const float f  = pos * (PI_F * (1.f + j2 * (127.f / 15.f)));
                        const float cf = __cosf(f), sf = __sinf(f);
                        const float res = (d & 1) ? (v * cf + other * sf)
                                                  : (v * cf - other * sf);
                        _Float16* dp = (sec == 0) ? qb : kb;
                        dp[(((size_t)(bt * NH + head)) * SEQ + s) * DH + d] = (_Float16)res;
                    }
                }
            }
        }
    } else {
#pragma unroll
        for (int i = 0; i < 2; ++i)
#pragma unroll
            for (int reg = 0; reg < 4; ++reg) {
                const int r = row0 + wr + i * 16 + (lane >> 4) * 4 + reg;
#pragma unroll
                for (int j = 0; j < 2; ++j) {
                    const int n = col0 + wc + j * 16 + (lane & 15);
                    out[(size_t)r * N + n] = acc[i][j][reg] + bias[n];
                }
            }
    }
}

__device__ __forceinline__ void attn_tile(
    int t, const _Float16* __restrict__ qh, const _Float16* __restrict__ kh,
    const _Float16* __restrict__ vt, const int* __restrict__ topk,
    const float* __restrict__ ontk, _Float16* __restrict__ attnh, float* Ps)
{
    const int tid  = threadIdx.x;
    const int w    = tid >> 6;
    const int lane = tid & 63;
    const int bt   = t >> 8;
    const int head = (t >> 4) & 15;
    const int s0   = (t & 15) * QT;
    const int bh   = bt * NH + head;

    __syncthreads();   // protect LDS reuse from previous phase/tile

    // Q a-frags / K b-frags first (phase-A critical path)
    half8 aq[2], bk[2][4];
#pragma unroll
    for (int kk = 0; kk < 2; ++kk) {
        const int c8 = (kk * 4 + (lane >> 4)) * 8;
        aq[kk] = *(const half8*)(qh + ((size_t)bh * SEQ + s0 + (lane & 15)) * DH + c8);
#pragma unroll
        for (int j = 0; j < 4; ++j)
            bk[kk][j] = *(const half8*)(kh + ((size_t)bh * SEQ + w * 64 + j * 16 + (lane & 15)) * DH + c8);
    }
    int ki0[4], ki1[4], ki2[4];
#pragma unroll
    for (int qq = 0; qq < 4; ++qq) {
        const int* idxp = topk + ((size_t)bh * SEQ + s0 + w * 4 + qq) * KTOP;
        ki0[qq] = idxp[lane];
        ki1[qq] = idxp[lane + 64];
        ki2[qq] = idxp[(lane < 16) ? (lane + 128) : lane];
    }
    half8 bv[8];
    {
        const _Float16* vrow = vt + ((size_t)bh * DH + w * 16 + (lane & 15)) * SEQ
                                  + (lane >> 4) * 8;
#pragma unroll
        for (int ks = 0; ks < 8; ++ks)
            bv[ks] = *(const half8*)(vrow + ks * 32);
    }
    float on[4];
#pragma unroll
    for (int reg = 0; reg < 4; ++reg) {
        const int row = (lane >> 4) * 4 + reg;
        on[reg] = ontk[((size_t)bh * SEQ + s0 + row) * DH + w * 16 + (lane & 15)];
    }

    // Phase A: S[16][256]
    f32x4 acc[4] = {};
#pragma unroll
    for (int kk = 0; kk < 2; ++kk)
#pragma unroll
        for (int j = 0; j < 4; ++j)
            acc[j] = __builtin_amdgcn_mfma_f32_16x16x32_f16(aq[kk], bk[kk][j], acc[j], 0, 0, 0);
#pragma unroll
    for (int j = 0; j < 4; ++j)
#pragma unroll
        for (int reg = 0; reg < 4; ++reg) {
            const int row = (lane >> 4) * 4 + reg;
            const int col = w * 64 + j * 16 + (lane & 15);
            Ps[row * 256 + (col ^ ((row & 7) << 2))] = acc[j][reg];
        }
    __syncthreads();

    // Phase B: softmax + prob scatter (atomicAdd sums duplicate indices)
#pragma unroll
    for (int qq = 0; qq < 4; ++qq) {
        const int q  = w * 4 + qq;
        const int sw = (q & 7) << 2;
        float* prow  = Ps + q * 256;
        const float sv0 = prow[ki0[qq] ^ sw] * 0.125f;
        const float sv1 = prow[ki1[qq] ^ sw] * 0.125f;
        const float sv2 = (lane < 16) ? prow[ki2[qq] ^ sw] * 0.125f : -1e30f;
        float m = fmaxf(fmaxf(sv0, sv1), sv2);
#pragma unroll
        for (int off = 32; off; off >>= 1) m = fmaxf(m, __shfl_xor(m, off));
        const float e0 = __expf(sv0 - m);
        const float e1 = __expf(sv1 - m);
        const float e2 = (lane < 16) ? __expf(sv2 - m) : 0.f;
        float z = e0 + e1 + e2;
#pragma unroll
        for (int off = 32; off; off >>= 1) z += __shfl_xor(z, off);
        const float inv = 1.f / z;
#pragma unroll
        for (int c2 = 0; c2 < 4; ++c2) prow[lane + c2 * 64] = 0.f;
        atomicAdd(&prow[ki0[qq] ^ sw], e0 * inv);
        atomicAdd(&prow[ki1[qq] ^ sw], e1 * inv);
        if (lane < 16) atomicAdd(&prow[ki2[qq] ^ sw], e2 * inv);
    }
    __syncthreads();

    // Phase C: out[16][64] = P.V ; wave w owns d-cols w*16..+15
    f32x4 oacc = {};
#pragma unroll
    for (int ks = 0; ks < 8; ++ks) {
        const int ra = lane & 15;
        const int b0 = ks * 32 + (lane >> 4) * 8;
        const int sw = (ra & 7) << 2;
        const float4 p0 = *(const float4*)(Ps + ra * 256 + (b0 ^ sw));
        const float4 p1 = *(const float4*)(Ps + ra * 256 + ((b0 + 4) ^ sw));
        half8 af;
        af[0] = (_Float16)p0.x; af[1] = (_Float16)p0.y;
        af[2] = (_Float16)p0.z; af[3] = (_Float16)p0.w;
        af[4] = (_Float16)p1.x; af[5] = (_Float16)p1.y;
        af[6] = (_Float16)p1.z; af[7] = (_Float16)p1.w;
        oacc = __builtin_amdgcn_mfma_f32_16x16x32_f16(af, bv[ks], oacc, 0, 0, 0);
    }
#pragma unroll
    for (int reg = 0; reg < 4; ++reg) {
        const int row = (lane >> 4) * 4 + reg;
        const int d   = w * 16 + (lane & 15);
        const int s   = s0 + row;
        attnh[((size_t)(bt * SEQ + s)) * DIMF + head * DH + d] = (_Float16)(oacc[reg] + on[reg]);
    }
}

// ---------------------------------------------------------------------------
// fused cooperative kernel: cvt -> [sync] -> qkv GEMM+RoPE -> [sync] ->
// attention -> [sync] -> out-proj GEMM
// ---------------------------------------------------------------------------
__global__ __launch_bounds__(256)
void fused_kernel(const float* __restrict__ x, const float* __restrict__ wq32,
                  const float* __restrict__ wo32, const float* __restrict__ b_out,
                  const float* __restrict__ ontk, const int* __restrict__ topk,
                  float* __restrict__ out,
                  _Float16* xh, _Float16* wqh, _Float16* woh, _Float16* attnh,
                  _Float16* qhb, _Float16* khb, _Float16* vtb)
{
    __shared__ __align__(16) char smem[16384];
    _Float16* As = (_Float16*)smem;
    _Float16* Bs = (_Float16*)(smem + 8192);
    float*    Ps = (float*)smem;

    cg::grid_group grid = cg::this_grid();
    const int bid = blockIdx.x;
    const int nb  = gridDim.x;

    // phase 0: fp32 -> fp16 (x, w_qkv, w_out)
    for (int q = bid * 256 + threadIdx.x; q < NTOT; q += nb * 256) {
        const float* s; _Float16* d; int off;
        if (q < N0Q)            { s = x;    d = xh;  off = q; }
        else if (q < N0Q + N1Q) { s = wq32; d = wqh; off = q - N0Q; }
        else                    { s = wo32; d = woh; off = q - (N0Q + N1Q); }
        const float4 v = *(const float4*)(s + (size_t)off * 4);
        half4v h;
        h[0] = (_Float16)v.x; h[1] = (_Float16)v.y;
        h[2] = (_Float16)v.z; h[3] = (_Float16)v.w;
        *(half4v*)(d + (size_t)off * 4) = h;
    }
    grid.sync();

    // phase 1: qkv projection + RoPE (384 tiles of 64x64)
    for (int t = bid; t < 384; t += nb)
        gemm_tile<0>(xh, wqh, DIMF, 3072, (t / 48) * 64, (t % 48) * 64,
                     qhb, khb, vtb, nullptr, nullptr, As, Bs);
    grid.sync();

    // phase 2: top-k attention (512 tiles, one per block)
    for (int t = bid; t < 512; t += nb)
        attn_tile(t, qhb, khb, vtb, topk, ontk, attnh, Ps);
    grid.sync();

    // phase 3: output projection + bias (128 tiles of 64x64)
    for (int t = bid; t < 128; t += nb)
        gemm_tile<1>(attnh, woh, DIMF, DIMF, (t >> 4) * 64, (t & 15) * 64,
                     nullptr, nullptr, nullptr, b_out, out, As, Bs);
}

// ---------------------------------------------------------------------------
// fallback standalone kernels (round-6 verified path)
// ---------------------------------------------------------------------------
__global__ __launch_bounds__(256)
void cvt3_kernel(const float* __restrict__ a, const float* __restrict__ b,
                 const float* __restrict__ c,
                 _Float16* __restrict__ da, _Float16* __restrict__ db,
                 _Float16* __restrict__ dc)
{
    int q = blockIdx.x * 256 + threadIdx.x;
    const float* s; _Float16* d; int off;
    if (q < N0Q)            { s = a; d = da; off = q; }
    else if (q < N0Q + N1Q) { s = b; d = db; off = q - N0Q; }
    else                    { s = c; d = dc; off = q - (N0Q + N1Q); }
    const float4 v = *(const float4*)(s + (size_t)off * 4);
    half4v h;
    h[0] = (_Float16)v.x; h[1] = (_Float16)v.y;
    h[2] = (_Float16)v.z; h[3] = (_Float16)v.w;
    *(half4v*)(d + (size_t)off * 4) = h;
}

template <int MODE>
__global__ __launch_bounds__(256)
void gemm_f16_kernel(const _Float16* __restrict__ A, const _Float16* __restrict__ B,
                     int N,
                     _Float16* __restrict__ qb, _Float16* __restrict__ kb,
                     _Float16* __restrict__ vb,
                     const float* __restrict__ bias, float* __restrict__ out)
{
    __shared__ __align__(16) _Float16 As[64 * 64];
    __shared__ __align__(16) _Float16 Bs[64 * 64];
    gemm_tile<MODE>(A, B, DIMF, N, blockIdx.y * 64, blockIdx.x * 64,
                    qb, kb, vb, bias, out, As, Bs);
}

__global__ __launch_bounds__(256)
void attn_reg16_kernel(const _Float16* __restrict__ qh, const _Float16* __restrict__ kh,
                       const _Float16* __restrict__ vt, const int* __restrict__ topk,
                       const float* __restrict__ ontk, _Float16* __restrict__ attnh)
{
    __shared__ __align__(16) float Ps[QT * 256];
    attn_tile(blockIdx.x, qh, kh, vt, topk, ontk, attnh, Ps);
}

// ---------------------------------------------------------------------------
extern "C" void kernel_launch(void* const* d_in, const int* in_sizes, int n_in,
                              void* d_out, int out_size, void* d_ws, size_t ws_size,
                              hipStream_t stream) {
    const float* x     = (const float*)d_in[0];
    const float* w_qkv = (const float*)d_in[1];
    const float* w_out = (const float*)d_in[2];
    const float* b_out = (const float*)d_in[3];
    const float* ontk  = (const float*)d_in[4];
    const int*   topk  = (const int*)d_in[5];
    float* out = (float*)d_out;

    const size_t QE = (size_t)BTN * NH * SEQ * DH;   // 524288

    _Float16* xh    = (_Float16*)d_ws;
    _Float16* wqh   = xh + 524288;
    _Float16* woh   = wqh + 3145728;
    _Float16* attnh = woh + 1048576;
    _Float16* qhb   = attnh + QE;
    _Float16* khb   = qhb + QE;
    _Float16* vtb   = khb + QE;

    void* kargs[] = { (void*)&x, (void*)&w_qkv, (void*)&w_out, (void*)&b_out,
                      (void*)&ontk, (void*)&topk, (void*)&out,
                      (void*)&xh, (void*)&wqh, (void*)&woh, (void*)&attnh,
                      (void*)&qhb, (void*)&khb, (void*)&vtb };

    hipError_t e = hipLaunchCooperativeKernel((const void*)fused_kernel,
                                              dim3(512), dim3(256), kargs, 0, stream);
    if (e != hipSuccess) {
        // fallback: 4-kernel round-6 path
        cvt3_kernel<<<NTOT / 256, 256, 0, stream>>>(x, w_qkv, w_out, xh, wqh, woh);
        gemm_f16_kernel<0><<<dim3(3072 / 64, 512 / 64), 256, 0, stream>>>(
            xh, wqh, 3072, qhb, khb, vtb, nullptr, nullptr);
        attn_reg16_kernel<<<BTN * NH * (SEQ / QT), 256, 0, stream>>>(
            qhb, khb, vtb, topk, ontk, attnh);
        gemm_f16_kernel<1><<<dim3(1024 / 64, 512 / 64), 256, 0, stream>>>(
            attnh, woh, 1024, nullptr, nullptr, nullptr, b_out, out);
    }
}

// Round 8
// 52.513 us; speedup vs baseline: 4.4279x; 4.4279x over previous
//
#include <hip/hip_runtime.h>
#include <hip/hip_bf16.h>
#include <math.h>

// SpatialAxialAttention: B*T=2, H=W=16, dim=1024, HEADS=16, DIM_HEAD=64, K=144
#define BTN   2
#define NH    16
#define SEQ   256
#define DH    64
#define DIMF  1024
#define KTOP  144
#define QT    16
#define PI_F  3.14159265358979323846f

typedef _Float16 half8 __attribute__((ext_vector_type(8)));
typedef float f32x4 __attribute__((ext_vector_type(4)));

#define GLDS(src, dst) __builtin_amdgcn_global_load_lds( \
        (const __attribute__((address_space(1))) void*)(src), \
        (__attribute__((address_space(3))) void*)(dst), 16, 0, 0)

// ---------------------------------------------------------------------------
// Mixed-precision MFMA NT-GEMM, self-converting (no separate cvt pass).
// 64x64 tile, BK=64, 256 threads (4 waves, 2x2 32x32 frags each).
// B (weights) is ALWAYS fp32: staged raw to LDS via global_load_lds with a
//   32B-granule XOR swizzle pre-applied to the global source; converted
//   fp32->fp16 on the frag read (2x ds_read_b128 + cvt).
// A: MODE 0 = fp32 (x), same fp32-LDS path. MODE 1 = fp16 (attnh) via the
//   verified fp16 global_load_lds path (16B-chunk XOR swizzle).
// MODE 0 epilogue: split qkv -> RoPE q,k -> fp16 (bt,head,s,d); v -> fp16
//   transposed (bt,head,d,s). MODE 1: +bias, fp32 row-major store.
// ---------------------------------------------------------------------------
template <int MODE>
__global__ __launch_bounds__(256)
void gemm_mixed_kernel(const float* __restrict__ A32, const _Float16* __restrict__ A16,
                       const float* __restrict__ B32, int N,
                       _Float16* __restrict__ qb, _Float16* __restrict__ kb,
                       _Float16* __restrict__ vb,
                       const float* __restrict__ bias, float* __restrict__ out)
{
    // MODE 0: As32 fp32 16KB + Bs32 fp32 16KB. MODE 1: As 8KB fp16 + Bs32 16KB.
    __shared__ __align__(16) float Bs32[64 * 64];
    __shared__ __align__(16) float As32[(MODE == 0) ? 64 * 64 : 32 * 64];
    _Float16* As16 = (_Float16*)As32;

    const int Kd   = DIMF;
    const int tid  = threadIdx.x;
    const int wave = tid >> 6;
    const int lane = tid & 63;
    const int row0 = blockIdx.y * 64;
    const int col0 = blockIdx.x * 64;
    const int wr = (wave >> 1) * 32;
    const int wc = (wave & 1) * 32;

    // fp32 staging coords: each GLDS covers 4 rows (256B each) x 16 chunks(16B)
    const int rl4 = lane >> 4;      // row within 4-row group
    const int cl16 = lane & 15;     // 16B chunk within row
    // fp16 staging coords (MODE 1 A): 8 rows x 8 chunks
    const int rl8 = lane >> 3;
    const int cl8 = lane & 7;

    f32x4 acc[2][2] = {};

    for (int kt = 0; kt < Kd; kt += 64) {
        __syncthreads();
        // ---- stage A ----
        if (MODE == 0) {
#pragma unroll
            for (int h = 0; h < 4; ++h) {
                const int r = wave * 16 + h * 4 + rl4;
                // src float offset within row: granule (cl16>>1)^(r&7), half cl16&1
                const int co = ((((cl16 >> 1) ^ (r & 7)) << 3) + ((cl16 & 1) << 2));
                GLDS(A32 + (size_t)(row0 + r) * Kd + kt + co,
                     As32 + (wave * 16 + h * 4) * 64);
            }
        } else {
#pragma unroll
            for (int h = 0; h < 2; ++h) {
                const int rbase = wave * 16 + h * 8;
                const int rA = rbase + rl8;
                GLDS(A16 + (size_t)(row0 + rA) * Kd + kt + ((cl8 ^ (rA & 7)) * 8),
                     As16 + rbase * 64);
            }
        }
        // ---- stage B (fp32) ----
#pragma unroll
        for (int h = 0; h < 4; ++h) {
            const int r = wave * 16 + h * 4 + rl4;
            const int co = ((((cl16 >> 1) ^ (r & 7)) << 3) + ((cl16 & 1) << 2));
            GLDS(B32 + (size_t)(col0 + r) * Kd + kt + co,
                 Bs32 + (wave * 16 + h * 4) * 64);
        }
        __syncthreads();

#pragma unroll
        for (int kh = 0; kh < 2; ++kh) {
            half8 a[2], b[2];
            const int g = kh * 4 + (lane >> 4);   // 8-element granule index
#pragma unroll
            for (int i = 0; i < 2; ++i) {
                const int ra = wr + i * 16 + (lane & 15);
                if (MODE == 0) {
                    const float* p = As32 + ra * 64 + ((g ^ (ra & 7)) * 8);
                    const f32x4 lo = *(const f32x4*)p;
                    const f32x4 hi = *(const f32x4*)(p + 4);
#pragma unroll
                    for (int t = 0; t < 4; ++t) {
                        a[i][t]     = (_Float16)lo[t];
                        a[i][t + 4] = (_Float16)hi[t];
                    }
                } else {
                    a[i] = *(const half8*)(As16 + ra * 64 + ((g ^ (ra & 7)) * 8));
                }
                const int rb = wc + i * 16 + (lane & 15);
                const float* q = Bs32 + rb * 64 + ((g ^ (rb & 7)) * 8);
                const f32x4 lo = *(const f32x4*)q;
                const f32x4 hi = *(const f32x4*)(q + 4);
#pragma unroll
                for (int t = 0; t < 4; ++t) {
                    b[i][t]     = (_Float16)lo[t];
                    b[i][t + 4] = (_Float16)hi[t];
                }
            }
#pragma unroll
            for (int i = 0; i < 2; ++i)
#pragma unroll
                for (int j = 0; j < 2; ++j)
                    acc[i][j] = __builtin_amdgcn_mfma_f32_16x16x32_f16(a[i], b[j], acc[i][j], 0, 0, 0);
        }
    }

    // C/D layout: col = lane&15, row = (lane>>4)*4 + reg
    if (MODE == 0) {
#pragma unroll
        for (int i = 0; i < 2; ++i) {
#pragma unroll
            for (int reg = 0; reg < 4; ++reg) {
                const int r  = row0 + wr + i * 16 + (lane >> 4) * 4 + reg;
                const int bt = r >> 8;
                const int s  = r & 255;
                const int hh = s >> 4;
                const int ww = s & 15;
#pragma unroll
                for (int j = 0; j < 2; ++j) {
                    const float v     = acc[i][j][reg];
                    const float other = __shfl_xor(v, 1);   // RoPE pair partner
                    const int n    = col0 + wc + j * 16 + (lane & 15);
                    const int sec  = n >> 10;       // 0=q,1=k,2=v
                    const int oi   = n & 1023;
                    const int head = oi >> 6;
                    const int d    = oi & 63;
                    if (sec == 2) {
                        vb[(((size_t)(bt * NH + head)) * DH + d) * SEQ + s] = (_Float16)v;
                    } else {
                        const int de  = d & ~1;
                        const int j2  = (de < 32) ? (de >> 1) : ((de - 32) >> 1);
                        const float pos = (de < 32) ? (-1.f + hh * (2.f / 15.f))
                                                    : (-1.f + ww * (2.f / 15.f));
                        const float f  = pos * (PI_F * (1.f + j2 * (127.f / 15.f)));
                        const float cf = __cosf(f), sf = __sinf(f);
                        const float res = (d & 1) ? (v * cf + other * sf)
                                                  : (v * cf - other * sf);
                        _Float16* dp = (sec == 0) ? qb : kb;
                        dp[(((size_t)(bt * NH + head)) * SEQ + s) * DH + d] = (_Float16)res;
                    }
                }
            }
        }
    } else {
#pragma unroll
        for (int i = 0; i < 2; ++i)
#pragma unroll
            for (int reg = 0; reg < 4; ++reg) {
                const int r = row0 + wr + i * 16 + (lane >> 4) * 4 + reg;
#pragma unroll
                for (int j = 0; j < 2; ++j) {
                    const int n = col0 + wc + j * 16 + (lane & 15);
                    out[(size_t)r * N + n] = acc[i][j][reg] + bias[n];
                }
            }
    }
}

// ---------------------------------------------------------------------------
// Register-resident dense-score top-k attention (round-6 verified).
// 512 blocks x 4 waves; LDS = 16KB score/prob matrix only.
// ---------------------------------------------------------------------------
__global__ __launch_bounds__(256)
void attn_reg16_kernel(const _Float16* __restrict__ qh, const _Float16* __restrict__ kh,
                       const _Float16* __restrict__ vt, const int* __restrict__ topk,
                       const float* __restrict__ ontk, _Float16* __restrict__ attnh)
{
    __shared__ __align__(16) float Ps[QT * 256];   // 16 KB

    const int tid  = threadIdx.x;
    const int w    = tid >> 6;
    const int lane = tid & 63;
    const int bid  = blockIdx.x;
    const int bt   = bid >> 8;
    const int head = (bid >> 4) & 15;
    const int s0   = (bid & 15) * QT;
    const int bh   = bt * NH + head;

    // Q a-frags / K b-frags first (phase-A critical path)
    half8 aq[2], bk[2][4];
#pragma unroll
    for (int kk = 0; kk < 2; ++kk) {
        const int c8 = (kk * 4 + (lane >> 4)) * 8;
        aq[kk] = *(const half8*)(qh + ((size_t)bh * SEQ + s0 + (lane & 15)) * DH + c8);
#pragma unroll
        for (int j = 0; j < 4; ++j)
            bk[kk][j] = *(const half8*)(kh + ((size_t)bh * SEQ + w * 64 + j * 16 + (lane & 15)) * DH + c8);
    }
    int ki0[4], ki1[4], ki2[4];
#pragma unroll
    for (int qq = 0; qq < 4; ++qq) {
        const int* idxp = topk + ((size_t)bh * SEQ + s0 + w * 4 + qq) * KTOP;
        ki0[qq] = idxp[lane];
        ki1[qq] = idxp[lane + 64];
        ki2[qq] = idxp[(lane < 16) ? (lane + 128) : lane];
    }
    half8 bv[8];
    {
        const _Float16* vrow = vt + ((size_t)bh * DH + w * 16 + (lane & 15)) * SEQ
                                  + (lane >> 4) * 8;
#pragma unroll
        for (int ks = 0; ks < 8; ++ks)
            bv[ks] = *(const half8*)(vrow + ks * 32);
    }
    float on[4];
#pragma unroll
    for (int reg = 0; reg < 4; ++reg) {
        const int row = (lane >> 4) * 4 + reg;
        on[reg] = ontk[((size_t)bh * SEQ + s0 + row) * DH + w * 16 + (lane & 15)];
    }

    // Phase A: S[16][256]
    f32x4 acc[4] = {};
#pragma unroll
    for (int kk = 0; kk < 2; ++kk)
#pragma unroll
        for (int j = 0; j < 4; ++j)
            acc[j] = __builtin_amdgcn_mfma_f32_16x16x32_f16(aq[kk], bk[kk][j], acc[j], 0, 0, 0);
#pragma unroll
    for (int j = 0; j < 4; ++j)
#pragma unroll
        for (int reg = 0; reg < 4; ++reg) {
            const int row = (lane >> 4) * 4 + reg;
            const int col = w * 64 + j * 16 + (lane & 15);
            Ps[row * 256 + (col ^ ((row & 7) << 2))] = acc[j][reg];
        }
    __syncthreads();

    // Phase B: softmax + prob scatter (atomicAdd sums duplicate indices)
#pragma unroll
    for (int qq = 0; qq < 4; ++qq) {
        const int q  = w * 4 + qq;
        const int sw = (q & 7) << 2;
        float* prow  = Ps + q * 256;
        const float sv0 = prow[ki0[qq] ^ sw] * 0.125f;
        const float sv1 = prow[ki1[qq] ^ sw] * 0.125f;
        const float sv2 = (lane < 16) ? prow[ki2[qq] ^ sw] * 0.125f : -1e30f;
        float m = fmaxf(fmaxf(sv0, sv1), sv2);
#pragma unroll
        for (int off = 32; off; off >>= 1) m = fmaxf(m, __shfl_xor(m, off));
        const float e0 = __expf(sv0 - m);
        const float e1 = __expf(sv1 - m);
        const float e2 = (lane < 16) ? __expf(sv2 - m) : 0.f;
        float z = e0 + e1 + e2;
#pragma unroll
        for (int off = 32; off; off >>= 1) z += __shfl_xor(z, off);
        const float inv = 1.f / z;
#pragma unroll
        for (int c2 = 0; c2 < 4; ++c2) prow[lane + c2 * 64] = 0.f;
        atomicAdd(&prow[ki0[qq] ^ sw], e0 * inv);
        atomicAdd(&prow[ki1[qq] ^ sw], e1 * inv);
        if (lane < 16) atomicAdd(&prow[ki2[qq] ^ sw], e2 * inv);
    }
    __syncthreads();

    // Phase C: out[16][64] = P.V ; wave w owns d-cols w*16..+15
    f32x4 oacc = {};
#pragma unroll
    for (int ks = 0; ks < 8; ++ks) {
        const int ra = lane & 15;
        const int b0 = ks * 32 + (lane >> 4) * 8;
        const int sw = (ra & 7) << 2;
        const float4 p0 = *(const float4*)(Ps + ra * 256 + (b0 ^ sw));
        const float4 p1 = *(const float4*)(Ps + ra * 256 + ((b0 + 4) ^ sw));
        half8 af;
        af[0] = (_Float16)p0.x; af[1] = (_Float16)p0.y;
        af[2] = (_Float16)p0.z; af[3] = (_Float16)p0.w;
        af[4] = (_Float16)p1.x; af[5] = (_Float16)p1.y;
        af[6] = (_Float16)p1.z; af[7] = (_Float16)p1.w;
        oacc = __builtin_amdgcn_mfma_f32_16x16x32_f16(af, bv[ks], oacc, 0, 0, 0);
    }
#pragma unroll
    for (int reg = 0; reg < 4; ++reg) {
        const int row = (lane >> 4) * 4 + reg;
        const int d   = w * 16 + (lane & 15);
        const int s   = s0 + row;
        attnh[((size_t)(bt * SEQ + s)) * DIMF + head * DH + d] = (_Float16)(oacc[reg] + on[reg]);
    }
}

// ---------------------------------------------------------------------------
extern "C" void kernel_launch(void* const* d_in, const int* in_sizes, int n_in,
                              void* d_out, int out_size, void* d_ws, size_t ws_size,
                              hipStream_t stream) {
    const float* x     = (const float*)d_in[0];
    const float* w_qkv = (const float*)d_in[1];
    const float* w_out = (const float*)d_in[2];
    const float* b_out = (const float*)d_in[3];
    const float* ontk  = (const float*)d_in[4];
    const int*   topk  = (const int*)d_in[5];
    float* out = (float*)d_out;

    const size_t QE = (size_t)BTN * NH * SEQ * DH;   // 524288

    _Float16* attnh = (_Float16*)d_ws;               // 512x1024 fp16
    _Float16* qhb   = attnh + (size_t)512 * 1024;
    _Float16* khb   = qhb + QE;
    _Float16* vtb   = khb + QE;

    // 1) qkv projection (fp32 inputs, self-converting) + RoPE
    gemm_mixed_kernel<0><<<dim3(3072 / 64, 512 / 64), 256, 0, stream>>>(
        x, nullptr, w_qkv, 3072, qhb, khb, vtb, nullptr, nullptr);

    // 2) register-resident top-k attention (512 blocks)
    attn_reg16_kernel<<<BTN * NH * (SEQ / QT), 256, 0, stream>>>(
        qhb, khb, vtb, topk, ontk, attnh);

    // 3) output projection (fp16 A, fp32 w_out self-converting) + bias
    gemm_mixed_kernel<1><<<dim3(1024 / 64, 512 / 64), 256, 0, stream>>>(
        nullptr, attnh, w_out, 1024, nullptr, nullptr, nullptr, b_out, out);
}